// Round 15
// baseline (78.214 us; speedup 1.0000x reference)
//
#include <hip/hip_runtime.h>
#include <hip/hip_bf16.h>
#include <math.h>

typedef __attribute__((ext_vector_type(8))) short short8;
typedef __attribute__((ext_vector_type(16))) float f32x16;

#define NB 4096
#define DIM 128
// sqrt(20 * log2(e)) folded into BOTH operands: acc = 28.8539*dot (log2 units)
#define SQS 5.3715828f

// Raw v_exp_f32 (domain |x|<=28.9 is far from denormal; 1 instr, exact here).
#if __has_builtin(__builtin_amdgcn_exp2f)
#define EX2(x) __builtin_amdgcn_exp2f(x)
#else
#define EX2(x) exp2f(x)
#endif

__device__ inline unsigned short f2bf(float f) {
  unsigned int u = __builtin_bit_cast(unsigned int, f);
  u += 0x7FFFu + ((u >> 16) & 1u);
  return (unsigned short)(u >> 16);
}

__device__ inline float wave_sum(float v) {
#pragma unroll
  for (int off = 32; off >= 1; off >>= 1) v += __shfl_xor(v, off, 64);
  return v;
}

// Parallel int64-vs-int32 links detect (all odd words zero <=> int64) + out=0.
__global__ __launch_bounds__(64) void k_init(const int* links32, int* flag, float* out) {
  int t = threadIdx.x;
  bool ok = (links32[1 + 2 * t] == 0) && (links32[129 + 2 * t] == 0);
  unsigned long long m = __ballot(ok);
  if (t == 0) { *flag = (m == ~0ull) ? 1 : 0; out[0] = 0.0f; }
}

// Pair-per-wave gather + L2-normalize + f32 diag.
// Packs bf16 K-chunked layout Zc[16][4096][8], PRE-SCALED by SQS.
// diagn[p] = 20 * (zi_p . zj_p)  (natural-log units)
__global__ __launch_bounds__(256) void k_normalize(
    const float* __restrict__ emb, const int* __restrict__ links,
    const int* __restrict__ flag,
    unsigned short* __restrict__ Zic, unsigned short* __restrict__ Zjc,
    float* __restrict__ diagn) {
  int wid = threadIdx.x >> 6, lane = threadIdx.x & 63;
  int p = blockIdx.x * 4 + wid;   // pair index 0..4095
  int fl = *flag;
  int idx_i = fl ? links[4 * p + 0] : links[2 * p + 0];
  int idx_j = fl ? links[4 * p + 2] : links[2 * p + 1];
  const float* si = emb + (long long)idx_i * DIM;
  const float* sj = emb + (long long)idx_j * DIM;
  float a0 = si[lane], a1 = si[lane + 64];
  float b0 = sj[lane], b1 = sj[lane + 64];
  float sii = wave_sum(a0 * a0 + a1 * a1);
  float sjj = wave_sum(b0 * b0 + b1 * b1);
  float sij = wave_sum(a0 * b0 + a1 * b1);
  float ni = fmaxf(sqrtf(sii), 1e-12f);
  float nj = fmaxf(sqrtf(sjj), 1e-12f);
  if (lane == 0) diagn[p] = 20.0f * sij / (ni * nj);
  float wi = SQS / ni, wj = SQS / nj;
  size_t o0 = (((size_t)(lane >> 3) + 0) * NB + p) * 8 + (lane & 7);
  size_t o1 = (((size_t)(lane >> 3) + 8) * NB + p) * 8 + (lane & 7);
  Zic[o0] = f2bf(a0 * wi);
  Zic[o1] = f2bf(a1 * wi);
  Zjc[o0] = f2bf(b0 * wj);
  Zjc[o1] = f2bf(b1 * wj);
}

// FUSED pass, BARRIER-FREE main loop: the whole 128-row j-panel (yj+yi, 64 KB)
// is staged in LDS ONCE (16 load+ds_write per thread, ONE barrier), then
// 4 j-tiles of pure {ds_read -> 4 MFMA chains -> exp} with zero syncs —
// waves drift freely across phases (no per-tile lockstep, no vmcnt drains).
// Compute layout identical to R12 (verified): wave owns 32 rows of xi AND xj;
// chains AB=yj.xi, BB=yj.xj, AA=yi.xi, BA=yi.xj; raw v_exp_f32 epilogue.
// Layout-agnostic dual per-reg probe (verified R3-R14).
__global__ __launch_bounds__(256) void k_pass(
    const unsigned short* __restrict__ Zic, const unsigned short* __restrict__ Zjc,
    float* __restrict__ rowp_a, float* __restrict__ rowp_b) {
  __shared__ unsigned short yt[2][16][128][8];  // [side 0=yj,1=yi][chunk][row][e] 64 KB
  __shared__ float bufa[128], bufb[128];
  int tid = threadIdx.x, wid = tid >> 6, lane = tid & 63;
  if (tid < 128) { bufa[tid] = 0.0f; bufb[tid] = 0.0f; }

  int it0 = blockIdx.x * 128 + wid * 32;  // wave's 32 loss-rows
  int jb = blockIdx.y * 128;              // 4 j-tiles of 32
  int lr = lane & 31;
  int hi = lane >> 5;

  // stage the whole panel: piece p = q*256+tid; s=p>>11, c=(p>>7)&15, row=p&127
#pragma unroll
  for (int q = 0; q < 16; ++q) {
    int p = q * 256 + tid;
    int s = p >> 11, c = (p >> 7) & 15, row = p & 127;
    const unsigned short* Zs = s ? Zic : Zjc;
    *reinterpret_cast<short8*>(&yt[s][c][row][0]) =
        *reinterpret_cast<const short8*>(Zs + ((size_t)c * NB + jb + row) * 8);
  }

  // --- dual per-reg layout probe (overlaps staging latency) ---
  short8 pj, pc;
  unsigned short blr = f2bf((float)lr);
#pragma unroll
  for (int e = 0; e < 8; ++e) { pj[e] = (short)blr; pc[e] = (short)0x3D80; }
  f32x16 pr = {}, pn = {};
  pr = __builtin_amdgcn_mfma_f32_32x32x16_bf16(pj, pc, pr, 0, 0, 0);
  pn = __builtin_amdgcn_mfma_f32_32x32x16_bf16(pc, pj, pn, 0, 0, 0);
  unsigned int dmask = 0;
  int imv[4] = {0, 0, 0, 0};
#pragma unroll
  for (int r = 0; r < 16; ++r) {
    int jm = (int)(pr[r] + 0.5f), im = (int)(pn[r] + 0.5f);
    dmask |= (unsigned)(jm == im) << r;
    imv[r >> 2] |= im << ((r & 3) * 8);
  }

  // X fragments for the whole j-loop: 32 rows of Zi and of Zj
  short8 xi[8], xj[8];
#pragma unroll
  for (int ks = 0; ks < 8; ++ks) {
    size_t o = ((size_t)(ks * 2 + hi) * NB + (it0 + lr)) * 8;
    xi[ks] = *reinterpret_cast<const short8*>(Zic + o);
    xj[ks] = *reinterpret_cast<const short8*>(Zjc + o);
  }

  float ra[16], rb[16];
#pragma unroll
  for (int r = 0; r < 16; ++r) { ra[r] = 0.0f; rb[r] = 0.0f; }

  __syncthreads();  // the ONLY barrier before the reduce

  for (int jt = 0; jt < 4; ++jt) {
    int j0 = jb + jt * 32;
    bool dt = (j0 == it0);
    f32x16 pab = {}, pbb = {}, paa = {}, pba = {};
#pragma unroll
    for (int ks = 0; ks < 8; ++ks) {
      short8 yj = *reinterpret_cast<const short8*>(&yt[0][ks * 2 + hi][jt * 32 + lr][0]);
      short8 yi = *reinterpret_cast<const short8*>(&yt[1][ks * 2 + hi][jt * 32 + lr][0]);
      pab = __builtin_amdgcn_mfma_f32_32x32x16_bf16(yj, xi[ks], pab, 0, 0, 0);
      pbb = __builtin_amdgcn_mfma_f32_32x32x16_bf16(yj, xj[ks], pbb, 0, 0, 0);
      paa = __builtin_amdgcn_mfma_f32_32x32x16_bf16(yi, xi[ks], paa, 0, 0, 0);
      pba = __builtin_amdgcn_mfma_f32_32x32x16_bf16(yi, xj[ks], pba, 0, 0, 0);
    }
#pragma unroll
    for (int r = 0; r < 16; ++r) {
      float eab = EX2(pab[r]);
      float ebb = EX2(pbb[r]);
      float eaa = EX2(paa[r]);
      float eba = EX2(pba[r]);
      if (dt && ((dmask >> r) & 1u)) { ebb = 0.0f; eaa = 0.0f; }  // diag skips
      ra[r] += eab + eaa;
      rb[r] += ebb + eba;
    }
  }
  // LDS reduce (2 lanes x 16 regs share each output row)
#pragma unroll
  for (int r = 0; r < 16; ++r) {
    int im = (imv[r >> 2] >> ((r & 3) * 8)) & 0xFF;
    atomicAdd(&bufa[wid * 32 + im], ra[r]);
    atomicAdd(&bufb[wid * 32 + im], rb[r]);
  }
  __syncthreads();
  if (tid < 128) {
    atomicAdd(&rowp_a[blockIdx.x * 128 + tid], bufa[tid]);
    atomicAdd(&rowp_b[blockIdx.x * 128 + tid], bufb[tid]);
  }
}

// zero the rowp accumulators (k_pass now accumulates via global atomics,
// 32 adds per row total — negligible contention)
__global__ __launch_bounds__(256) void k_zero(float* rowp_a, float* rowp_b) {
  int i = blockIdx.x * 256 + threadIdx.x;
  if (i < NB) { rowp_a[i] = 0.0f; rowp_b[i] = 0.0f; }
}

// loss = mean(0.5*(ln sa + ln sb) - diagn)   (e^{+20} scale cancels in ln)
__global__ __launch_bounds__(256) void k_final(
    const float* __restrict__ rowp_a, const float* __restrict__ rowp_b,
    const float* __restrict__ diagn, float* __restrict__ out) {
  int i = blockIdx.x * 256 + threadIdx.x;
  float v = 0.5f * (logf(rowp_a[i]) + logf(rowp_b[i])) - diagn[i];
  v = wave_sum(v);
  __shared__ float sred[4];
  if ((threadIdx.x & 63) == 0) sred[threadIdx.x >> 6] = v;
  __syncthreads();
  if (threadIdx.x == 0)
    atomicAdd(out, (sred[0] + sred[1] + sred[2] + sred[3]) * (1.0f / NB));
}

extern "C" void kernel_launch(void* const* d_in, const int* in_sizes, int n_in,
                              void* d_out, int out_size, void* d_ws, size_t ws_size,
                              hipStream_t stream) {
  const float* emb = (const float*)d_in[0];
  const int* links = (const int*)d_in[1];
  char* ws = (char*)d_ws;
  unsigned short* Zic = (unsigned short*)(ws + 0);       // 1 MB
  unsigned short* Zjc = (unsigned short*)(ws + 1048576); // 1 MB
  float* rowp_a = (float*)(ws + 2097152);                // 16 KB
  float* rowp_b = (float*)(ws + 2113536);                // 16 KB
  float* diagn = (float*)(ws + 2129920);                 // 16 KB
  int* flag = (int*)(ws + 2146304);                      // 4 B
  float* out = (float*)d_out;

  hipLaunchKernelGGL(k_init, dim3(1), dim3(64), 0, stream, links, flag, out);
  hipLaunchKernelGGL(k_zero, dim3(16), dim3(256), 0, stream, rowp_a, rowp_b);
  hipLaunchKernelGGL(k_normalize, dim3(1024), dim3(256), 0, stream,
                     emb, links, flag, Zic, Zjc, diagn);
  hipLaunchKernelGGL(k_pass, dim3(32, 32), dim3(256), 0, stream,
                     Zic, Zjc, rowp_a, rowp_b);
  hipLaunchKernelGGL(k_final, dim3(16), dim3(256), 0, stream,
                     rowp_a, rowp_b, diagn, out);
}

// Round 16
// 77.142 us; speedup vs baseline: 1.0139x; 1.0139x over previous
//
#include <hip/hip_runtime.h>
#include <hip/hip_bf16.h>
#include <math.h>

typedef __attribute__((ext_vector_type(8))) short short8;
typedef __attribute__((ext_vector_type(16))) float f32x16;

#define NB 4096
#define DIM 128
// sqrt(20 * log2(e)) folded into BOTH operands: acc = 28.8539*dot (log2 units)
#define SQS 5.3715828f

// Raw v_exp_f32 (domain |x|<=28.9 is far from denormal; 1 instr, exact here).
#if __has_builtin(__builtin_amdgcn_exp2f)
#define EX2(x) __builtin_amdgcn_exp2f(x)
#else
#define EX2(x) exp2f(x)
#endif

__device__ inline unsigned short f2bf(float f) {
  unsigned int u = __builtin_bit_cast(unsigned int, f);
  u += 0x7FFFu + ((u >> 16) & 1u);
  return (unsigned short)(u >> 16);
}

__device__ inline float wave_sum(float v) {
#pragma unroll
  for (int off = 32; off >= 1; off >>= 1) v += __shfl_xor(v, off, 64);
  return v;
}

// Parallel int64-vs-int32 links detect (all odd words zero <=> int64) + out=0.
__global__ __launch_bounds__(64) void k_init(const int* links32, int* flag, float* out) {
  int t = threadIdx.x;
  bool ok = (links32[1 + 2 * t] == 0) && (links32[129 + 2 * t] == 0);
  unsigned long long m = __ballot(ok);
  if (t == 0) { *flag = (m == ~0ull) ? 1 : 0; out[0] = 0.0f; }
}

// Pair-per-wave gather + L2-normalize + f32 diag.
// Packs bf16 K-chunked layout Zc[16][4096][8], PRE-SCALED by SQS.
// diagn[p] = 20 * (zi_p . zj_p)  (natural-log units)
__global__ __launch_bounds__(256) void k_normalize(
    const float* __restrict__ emb, const int* __restrict__ links,
    const int* __restrict__ flag,
    unsigned short* __restrict__ Zic, unsigned short* __restrict__ Zjc,
    float* __restrict__ diagn) {
  int wid = threadIdx.x >> 6, lane = threadIdx.x & 63;
  int p = blockIdx.x * 4 + wid;   // pair index 0..4095
  int fl = *flag;
  int idx_i = fl ? links[4 * p + 0] : links[2 * p + 0];
  int idx_j = fl ? links[4 * p + 2] : links[2 * p + 1];
  const float* si = emb + (long long)idx_i * DIM;
  const float* sj = emb + (long long)idx_j * DIM;
  float a0 = si[lane], a1 = si[lane + 64];
  float b0 = sj[lane], b1 = sj[lane + 64];
  float sii = wave_sum(a0 * a0 + a1 * a1);
  float sjj = wave_sum(b0 * b0 + b1 * b1);
  float sij = wave_sum(a0 * b0 + a1 * b1);
  float ni = fmaxf(sqrtf(sii), 1e-12f);
  float nj = fmaxf(sqrtf(sjj), 1e-12f);
  if (lane == 0) diagn[p] = 20.0f * sij / (ni * nj);
  float wi = SQS / ni, wj = SQS / nj;
  size_t o0 = (((size_t)(lane >> 3) + 0) * NB + p) * 8 + (lane & 7);
  size_t o1 = (((size_t)(lane >> 3) + 8) * NB + p) * 8 + (lane & 7);
  Zic[o0] = f2bf(a0 * wi);
  Zic[o1] = f2bf(a1 * wi);
  Zjc[o0] = f2bf(b0 * wj);
  Zjc[o1] = f2bf(b1 * wj);
}

// FUSED pass, barrier-free main loop (R15 structure, verified).
// R15 lesson: plain __launch_bounds__(256) let the allocator chase occupancy
// and demote the "hoisted" xi/xj to scratch/remat (VGPR_Count=96 for ~180 live
// regs) — every jt iteration then carried a hidden global-latency round-trip.
// __launch_bounds__(256, 2) sets a 256-VGPR budget: state stays in registers.
__global__ __launch_bounds__(256, 2) void k_pass(
    const unsigned short* __restrict__ Zic, const unsigned short* __restrict__ Zjc,
    float* __restrict__ rowp_a, float* __restrict__ rowp_b) {
  __shared__ unsigned short yt[2][16][128][8];  // [side 0=yj,1=yi][chunk][row][e] 64 KB
  __shared__ float bufa[128], bufb[128];
  int tid = threadIdx.x, wid = tid >> 6, lane = tid & 63;
  if (tid < 128) { bufa[tid] = 0.0f; bufb[tid] = 0.0f; }

  int it0 = blockIdx.x * 128 + wid * 32;  // wave's 32 loss-rows
  int jb = blockIdx.y * 128;              // 4 j-tiles of 32
  int lr = lane & 31;
  int hi = lane >> 5;

  // stage the whole panel: piece p = q*256+tid; s=p>>11, c=(p>>7)&15, row=p&127
#pragma unroll
  for (int q = 0; q < 16; ++q) {
    int p = q * 256 + tid;
    int s = p >> 11, c = (p >> 7) & 15, row = p & 127;
    const unsigned short* Zs = s ? Zic : Zjc;
    *reinterpret_cast<short8*>(&yt[s][c][row][0]) =
        *reinterpret_cast<const short8*>(Zs + ((size_t)c * NB + jb + row) * 8);
  }

  // --- dual per-reg layout probe (overlaps staging latency) ---
  short8 pj, pc;
  unsigned short blr = f2bf((float)lr);
#pragma unroll
  for (int e = 0; e < 8; ++e) { pj[e] = (short)blr; pc[e] = (short)0x3D80; }
  f32x16 pr = {}, pn = {};
  pr = __builtin_amdgcn_mfma_f32_32x32x16_bf16(pj, pc, pr, 0, 0, 0);
  pn = __builtin_amdgcn_mfma_f32_32x32x16_bf16(pc, pj, pn, 0, 0, 0);
  unsigned int dmask = 0;
  int imv[4] = {0, 0, 0, 0};
#pragma unroll
  for (int r = 0; r < 16; ++r) {
    int jm = (int)(pr[r] + 0.5f), im = (int)(pn[r] + 0.5f);
    dmask |= (unsigned)(jm == im) << r;
    imv[r >> 2] |= im << ((r & 3) * 8);
  }

  // X fragments for the whole j-loop: 32 rows of Zi and of Zj
  short8 xi[8], xj[8];
#pragma unroll
  for (int ks = 0; ks < 8; ++ks) {
    size_t o = ((size_t)(ks * 2 + hi) * NB + (it0 + lr)) * 8;
    xi[ks] = *reinterpret_cast<const short8*>(Zic + o);
    xj[ks] = *reinterpret_cast<const short8*>(Zjc + o);
  }

  float ra[16], rb[16];
#pragma unroll
  for (int r = 0; r < 16; ++r) { ra[r] = 0.0f; rb[r] = 0.0f; }

  __syncthreads();  // the ONLY barrier before the reduce

  for (int jt = 0; jt < 4; ++jt) {
    int j0 = jb + jt * 32;
    bool dt = (j0 == it0);
    f32x16 pab = {}, pbb = {}, paa = {}, pba = {};
#pragma unroll
    for (int ks = 0; ks < 8; ++ks) {
      short8 yj = *reinterpret_cast<const short8*>(&yt[0][ks * 2 + hi][jt * 32 + lr][0]);
      short8 yi = *reinterpret_cast<const short8*>(&yt[1][ks * 2 + hi][jt * 32 + lr][0]);
      pab = __builtin_amdgcn_mfma_f32_32x32x16_bf16(yj, xi[ks], pab, 0, 0, 0);
      pbb = __builtin_amdgcn_mfma_f32_32x32x16_bf16(yj, xj[ks], pbb, 0, 0, 0);
      paa = __builtin_amdgcn_mfma_f32_32x32x16_bf16(yi, xi[ks], paa, 0, 0, 0);
      pba = __builtin_amdgcn_mfma_f32_32x32x16_bf16(yi, xj[ks], pba, 0, 0, 0);
    }
#pragma unroll
    for (int r = 0; r < 16; ++r) {
      float eab = EX2(pab[r]);
      float ebb = EX2(pbb[r]);
      float eaa = EX2(paa[r]);
      float eba = EX2(pba[r]);
      if (dt && ((dmask >> r) & 1u)) { ebb = 0.0f; eaa = 0.0f; }  // diag skips
      ra[r] += eab + eaa;
      rb[r] += ebb + eba;
    }
  }
  // LDS reduce (2 lanes x 16 regs share each output row)
#pragma unroll
  for (int r = 0; r < 16; ++r) {
    int im = (imv[r >> 2] >> ((r & 3) * 8)) & 0xFF;
    atomicAdd(&bufa[wid * 32 + im], ra[r]);
    atomicAdd(&bufb[wid * 32 + im], rb[r]);
  }
  __syncthreads();
  if (tid < 128) {
    atomicAdd(&rowp_a[blockIdx.x * 128 + tid], bufa[tid]);
    atomicAdd(&rowp_b[blockIdx.x * 128 + tid], bufb[tid]);
  }
}

// zero the rowp accumulators
__global__ __launch_bounds__(256) void k_zero(float* rowp_a, float* rowp_b) {
  int i = blockIdx.x * 256 + threadIdx.x;
  if (i < NB) { rowp_a[i] = 0.0f; rowp_b[i] = 0.0f; }
}

// loss = mean(0.5*(ln sa + ln sb) - diagn)   (e^{+20} scale cancels in ln)
__global__ __launch_bounds__(256) void k_final(
    const float* __restrict__ rowp_a, const float* __restrict__ rowp_b,
    const float* __restrict__ diagn, float* __restrict__ out) {
  int i = blockIdx.x * 256 + threadIdx.x;
  float v = 0.5f * (logf(rowp_a[i]) + logf(rowp_b[i])) - diagn[i];
  v = wave_sum(v);
  __shared__ float sred[4];
  if ((threadIdx.x & 63) == 0) sred[threadIdx.x >> 6] = v;
  __syncthreads();
  if (threadIdx.x == 0)
    atomicAdd(out, (sred[0] + sred[1] + sred[2] + sred[3]) * (1.0f / NB));
}

extern "C" void kernel_launch(void* const* d_in, const int* in_sizes, int n_in,
                              void* d_out, int out_size, void* d_ws, size_t ws_size,
                              hipStream_t stream) {
  const float* emb = (const float*)d_in[0];
  const int* links = (const int*)d_in[1];
  char* ws = (char*)d_ws;
  unsigned short* Zic = (unsigned short*)(ws + 0);       // 1 MB
  unsigned short* Zjc = (unsigned short*)(ws + 1048576); // 1 MB
  float* rowp_a = (float*)(ws + 2097152);                // 16 KB
  float* rowp_b = (float*)(ws + 2113536);                // 16 KB
  float* diagn = (float*)(ws + 2129920);                 // 16 KB
  int* flag = (int*)(ws + 2146304);                      // 4 B
  float* out = (float*)d_out;

  hipLaunchKernelGGL(k_init, dim3(1), dim3(64), 0, stream, links, flag, out);
  hipLaunchKernelGGL(k_zero, dim3(16), dim3(256), 0, stream, rowp_a, rowp_b);
  hipLaunchKernelGGL(k_normalize, dim3(1024), dim3(256), 0, stream,
                     emb, links, flag, Zic, Zjc, diagn);
  hipLaunchKernelGGL(k_pass, dim3(32, 32), dim3(256), 0, stream,
                     Zic, Zjc, rowp_a, rowp_b);
  hipLaunchKernelGGL(k_final, dim3(16), dim3(256), 0, stream,
                     rowp_a, rowp_b, diagn, out);
}